// Round 3
// baseline (661.957 us; speedup 1.0000x reference)
//
#include <hip/hip_runtime.h>

// ---------------------------------------------------------------------------
// EdgeFeatures (fp32 in / fp32 out):
//   out[i] = (e[i] @ Us_w^T + Us_b) + Vx[src[i]] + Vx[dst[i]]
//   Vx     = x @ Vs_w^T + Vs_b
// H=256, V=10000, E=300000.
// Round-2 structure: barrier-free K-loop.
//  - B half-tile (128x256 bf16 = 64KB) staged into LDS ONCE per block via
//    global_load_lds, in FRAGMENT ORDER (pre-permuted in ws by cvt_weights,
//    rule #21: linear LDS dest + permuted global source) so every
//    ds_read_b128 is base+lane*16 -> conflict-free.
//  - A loaded global->reg directly per wave (16 rows x 128B segments),
//    cvt fp32->bf16 in-reg, 2-deep double-buffered prefetch, NO barriers
//    inside the K-loop (the old 16 vmcnt(0)-draining barriers were the
//    latency bottleneck: 8x ~700cyc serial drains vs 640cyc MFMA).
//  - Epilogue: per-wave LDS transpose (aliases B LDS after one barrier) so
//    Vx gathers are bf16x4 and stores dwordx4 coalesced.
// ws layout: [0,128K) Us_w bf16 frag-order | [128K,256K) Vs_w | [256K,+5.12M) Vx
// ---------------------------------------------------------------------------

typedef __bf16 bf16_t;
typedef __bf16 bf16x4 __attribute__((ext_vector_type(4)));
typedef __bf16 bf16x8 __attribute__((ext_vector_type(8)));
typedef float f32x4 __attribute__((ext_vector_type(4)));
typedef float f32x8 __attribute__((ext_vector_type(8)));

#define HDIM 256
#define NV 10000
#define NE 300000

__device__ __forceinline__ void async16(const bf16_t* g, bf16_t* l) {
  __builtin_amdgcn_global_load_lds(
      (const __attribute__((address_space(1))) void*)g,
      (__attribute__((address_space(3))) void*)l, 16, 0, 0);
}

// fp32 -> bf16 convert + permute both 256x256 weights into fragment order.
// Chunk c (16B, 8 bf16) holds W[n][kb..kb+8) with:
//   h=c>>12 (n-half), g=(c>>6)&63 = kstep*8 + wn*4 + ni, lane=c&63
//   n = h*128 + wn*64 + ni*16 + (lane&15), kb = kstep*32 + (lane>>4)*8
// In-kernel: group (kstep,wn,ni) at byte kstep*8192+wn*4096+ni*1024, +lane*16.
__global__ __launch_bounds__(256) void cvt_weights(
    const float* __restrict__ us, const float* __restrict__ vs,
    bf16_t* __restrict__ us_o, bf16_t* __restrict__ vs_o) {
  const int c = blockIdx.x * 256 + threadIdx.x;  // 0..8191 (32 blocks)
  const int h = c >> 12;
  const int g = (c >> 6) & 63;
  const int ln = c & 63;
  const int n = h * 128 + ((g >> 2) & 1) * 64 + (g & 3) * 16 + (ln & 15);
  const int kb = (g >> 3) * 32 + (ln >> 4) * 8;
  const float* su = us + n * HDIM + kb;
  const float* sv = vs + n * HDIM + kb;
  f32x4 a0 = *(const f32x4*)su, a1 = *(const f32x4*)(su + 4);
  f32x4 b0 = *(const f32x4*)sv, b1 = *(const f32x4*)(sv + 4);
  f32x8 av = {a0[0], a0[1], a0[2], a0[3], a1[0], a1[1], a1[2], a1[3]};
  f32x8 bv = {b0[0], b0[1], b0[2], b0[3], b1[0], b1[1], b1[2], b1[3]};
  *(bf16x8*)(us_o + c * 8) = __builtin_convertvector(av, bf16x8);
  *(bf16x8*)(vs_o + c * 8) = __builtin_convertvector(bv, bf16x8);
}

template <bool FUSED>
__global__ __launch_bounds__(256) void gemm(
    const float* __restrict__ A,      // M x 256 fp32 (e or x)
    const bf16_t* __restrict__ Wb,    // frag-order 2x32768 bf16 (2 n-halves)
    const float* __restrict__ bias,   // 256 fp32
    const int* __restrict__ sIdxG,    // FUSED: src indices (E)
    const int* __restrict__ dIdxG,    // FUSED: dst indices (E)
    const bf16_t* __restrict__ Vx,    // FUSED: V x 256 bf16
    float* __restrict__ outF,         // FUSED: M x 256 fp32
    bf16_t* __restrict__ outB,        // !FUSED: M x 256 bf16 (Vx scratch)
    int M) {
  // LDS: [0,64K) B half-tile (frag order). Epilogue staging aliases [0,17408).
  __shared__ __align__(16) char smem[65536];

  const int tid = threadIdx.x;  // 0..255
  const int lane = tid & 63;
  const int wave = tid >> 6;
  const int wm = wave >> 1;  // wave row (0..1)
  const int wn = wave & 1;   // wave col (0..1)
  const int l15 = lane & 15;
  const int quad = lane >> 4;  // 0..3

  const int n0 = blockIdx.x * 128;   // n-half: x fast-varying -> L2-hot A
  const int row0 = blockIdx.y * 128;

  // --- B: stage whole 64KB half once (linear; ws already frag-ordered) ----
  const bf16_t* wsHalf = Wb + (size_t)blockIdx.x * 32768;
  bf16_t* lB = (bf16_t*)smem;
#pragma unroll
  for (int i = 0; i < 16; ++i) {
    const int c = tid + i * 256;
    async16(wsHalf + c * 8, lB + c * 8);
  }

  // --- A: per-mi row pointers (clamped), at column quad*8 -----------------
  const float* pA[4];
#pragma unroll
  for (int mi = 0; mi < 4; ++mi) {
    int r = row0 + wm * 64 + mi * 16 + l15;
    if (r >= M) r = M - 1;
    pA[mi] = A + (size_t)r * HDIM + quad * 8;
  }

  // 2-deep prefetch: bufA = even kstep, bufB = odd kstep
  f32x4 bufA[4][2], bufB[4][2];
#pragma unroll
  for (int mi = 0; mi < 4; ++mi) {
    bufA[mi][0] = *(const f32x4*)(pA[mi] + 0);
    bufA[mi][1] = *(const f32x4*)(pA[mi] + 4);
    bufB[mi][0] = *(const f32x4*)(pA[mi] + 32);
    bufB[mi][1] = *(const f32x4*)(pA[mi] + 36);
  }

  f32x4 acc[4][4];
#pragma unroll
  for (int mi = 0; mi < 4; ++mi)
#pragma unroll
    for (int ni = 0; ni < 4; ++ni) {
      f32x4 z = {0.f, 0.f, 0.f, 0.f};
      acc[mi][ni] = z;
    }

  const int bOff = wn * 4096 + lane * 16;  // byte offset within kstep group

  __syncthreads();  // B LDS ready (single drain; also covers A prefetch)

#pragma unroll 1  // keep dynamic: bounds reg pressure, preserves 2-deep pipe
  for (int i = 0; i < 4; ++i) {
    const int k0 = i * 64;
    // ---- even kstep t=2i (data in bufA) ----
    bf16x8 af[4];
#pragma unroll
    for (int mi = 0; mi < 4; ++mi) {
      f32x8 v = {bufA[mi][0][0], bufA[mi][0][1], bufA[mi][0][2], bufA[mi][0][3],
                 bufA[mi][1][0], bufA[mi][1][1], bufA[mi][1][2], bufA[mi][1][3]};
      af[mi] = __builtin_convertvector(v, bf16x8);
    }
    if (i < 3) {  // refill bufA for kstep 2i+2
#pragma unroll
      for (int mi = 0; mi < 4; ++mi) {
        bufA[mi][0] = *(const f32x4*)(pA[mi] + k0 + 64);
        bufA[mi][1] = *(const f32x4*)(pA[mi] + k0 + 68);
      }
    }
#pragma unroll
    for (int ni = 0; ni < 4; ++ni) {
      bf16x8 bfr = *(const bf16x8*)(smem + (2 * i) * 8192 + ni * 1024 + bOff);
#pragma unroll
      for (int mi = 0; mi < 4; ++mi)
        acc[mi][ni] = __builtin_amdgcn_mfma_f32_16x16x32_bf16(
            af[mi], bfr, acc[mi][ni], 0, 0, 0);
    }
    // ---- odd kstep t=2i+1 (data in bufB) ----
#pragma unroll
    for (int mi = 0; mi < 4; ++mi) {
      f32x8 v = {bufB[mi][0][0], bufB[mi][0][1], bufB[mi][0][2], bufB[mi][0][3],
                 bufB[mi][1][0], bufB[mi][1][1], bufB[mi][1][2], bufB[mi][1][3]};
      af[mi] = __builtin_convertvector(v, bf16x8);
    }
    if (i < 3) {  // refill bufB for kstep 2i+3
#pragma unroll
      for (int mi = 0; mi < 4; ++mi) {
        bufB[mi][0] = *(const f32x4*)(pA[mi] + k0 + 96);
        bufB[mi][1] = *(const f32x4*)(pA[mi] + k0 + 100);
      }
    }
#pragma unroll
    for (int ni = 0; ni < 4; ++ni) {
      bf16x8 bfr =
          *(const bf16x8*)(smem + (2 * i + 1) * 8192 + ni * 1024 + bOff);
#pragma unroll
      for (int mi = 0; mi < 4; ++mi)
        acc[mi][ni] = __builtin_amdgcn_mfma_f32_16x16x32_bf16(
            af[mi], bfr, acc[mi][ni], 0, 0, 0);
    }
  }

  __syncthreads();  // all waves done reading B LDS -> staging may alias it

  // --- epilogue: C/D layout col = lane&15, row = quad*4 + reg --------------
  // Stage acc(+bias) into per-wave [16][68] f32 LDS, re-read coalesced:
  // lane map row = lane>>2, 4-col chunk = (lane&3)*4 + i*16 -> bf16x4 gathers
  // + dwordx4 stores. DS in-order within wave => no barrier inside.
  float bcol[4];
#pragma unroll
  for (int ni = 0; ni < 4; ++ni)
    bcol[ni] = bias[n0 + wn * 64 + ni * 16 + l15];

  float* stage = (float*)smem + wave * (16 * 68);
  const int srow = lane >> 2;       // 0..15
  const int scol = (lane & 3) * 4;  // 0,4,8,12

#pragma unroll
  for (int mi = 0; mi < 4; ++mi) {
#pragma unroll
    for (int ni = 0; ni < 4; ++ni)
#pragma unroll
      for (int r = 0; r < 4; ++r)
        stage[(quad * 4 + r) * 68 + ni * 16 + l15] = acc[mi][ni][r] + bcol[ni];

    const int rl = wm * 64 + mi * 16 + srow;
    const int row = row0 + rl;
    if (row < M) {
      const float* sp = stage + srow * 68;
      if constexpr (FUSED) {
        const int si = sIdxG[row];
        const int di = dIdxG[row];
        const bf16_t* vs = Vx + (size_t)si * HDIM + n0 + wn * 64;
        const bf16_t* vd = Vx + (size_t)di * HDIM + n0 + wn * 64;
        float* op = outF + (size_t)row * HDIM + n0 + wn * 64;
#pragma unroll
        for (int i = 0; i < 4; ++i) {
          const int c = i * 16 + scol;
          f32x4 a = *(const f32x4*)(sp + c);
          f32x4 sf = __builtin_convertvector(*(const bf16x4*)(vs + c), f32x4);
          f32x4 df = __builtin_convertvector(*(const bf16x4*)(vd + c), f32x4);
          *(f32x4*)(op + c) = a + sf + df;
        }
      } else {
        bf16_t* op = outB + (size_t)row * HDIM + n0 + wn * 64;
#pragma unroll
        for (int i = 0; i < 4; ++i) {
          const int c = i * 16 + scol;
          f32x4 a = *(const f32x4*)(sp + c);
          *(bf16x4*)(op + c) = __builtin_convertvector(a, bf16x4);
        }
      }
    }
  }
}

extern "C" void kernel_launch(void* const* d_in, const int* in_sizes, int n_in,
                              void* d_out, int out_size, void* d_ws,
                              size_t ws_size, hipStream_t stream) {
  const float* x = (const float*)d_in[0];     // (V, H) fp32
  const float* e = (const float*)d_in[1];     // (E, H) fp32
  const int* edge = (const int*)d_in[2];      // (2, E) int32: src then dst
  const float* Us_w = (const float*)d_in[3];  // (H, H) fp32
  const float* Us_b = (const float*)d_in[4];  // (H,) fp32
  const float* Vs_w = (const float*)d_in[5];  // (H, H) fp32
  const float* Vs_b = (const float*)d_in[6];  // (H,) fp32
  float* out = (float*)d_out;                 // (E, H) fp32

  bf16_t* us_w_b = (bf16_t*)d_ws;                         // 128 KB frag-order
  bf16_t* vs_w_b = (bf16_t*)((char*)d_ws + (128 << 10));  // 128 KB frag-order
  bf16_t* Vx = (bf16_t*)((char*)d_ws + (256 << 10));      // 5.12 MB

  dim3 blk(256, 1, 1);

  cvt_weights<<<dim3(32, 1, 1), blk, 0, stream>>>(Us_w, Vs_w, us_w_b, vs_w_b);

  dim3 g1(2, (NV + 127) / 128, 1);
  gemm<false><<<g1, blk, 0, stream>>>(x, vs_w_b, Vs_b, nullptr, nullptr,
                                      nullptr, nullptr, Vx, NV);

  dim3 g2(2, (NE + 127) / 128, 1);
  gemm<true><<<g2, blk, 0, stream>>>(e, us_w_b, Us_b, edge, edge + NE, Vx, out,
                                     nullptr, NE);
}

// Round 4
// 563.510 us; speedup vs baseline: 1.1747x; 1.1747x over previous
//
#include <hip/hip_runtime.h>

// ---------------------------------------------------------------------------
// EdgeFeatures (fp32 in / fp32 out):
//   out[i] = (e[i] @ Us_w^T + Us_b) + Vx[src[i]] + Vx[dst[i]]
//   Vx     = x @ Vs_w^T + Vs_b
// H=256, V=10000, E=300000.
// Round-4 structure: all-of-A-upfront, barrier-free K burst.
//  - B half (128x256 bf16 = 64KB) staged once per block via global_load_lds
//    in FRAGMENT ORDER (ws pre-permuted by cvt_weights; rule #21) so K-loop
//    ds_read_b128 = group_base + lane*16 -> conflict-free.
//  - A: wave = 32 rows x 128 cols; the wave's FULL K-slice (32 x f32x4 =
//    128 VGPR) is issued before the single barrier. The barrier's vmcnt(0)
//    drain IS the BW phase (512B/lane in flight, both resident blocks
//    stream concurrently); the 8-kstep MFMA burst then runs stall-free.
//    (Round-3 failed: 2-deep refill -> 100cyc issue-to-use vs 500cyc
//    latency + 11% occupancy = per-kstep stalls.)
//  - Epilogue: per-wave LDS transpose (aliases B LDS after one barrier) so
//    Vx gathers are bf16x4 and stores dwordx4 coalesced.
// ws layout: [0,128K) Us_w bf16 frag-order | [128K,256K) Vs_w | [256K,+5.12M) Vx
// ---------------------------------------------------------------------------

typedef __bf16 bf16_t;
typedef __bf16 bf16x4 __attribute__((ext_vector_type(4)));
typedef __bf16 bf16x8 __attribute__((ext_vector_type(8)));
typedef float f32x4 __attribute__((ext_vector_type(4)));
typedef float f32x8 __attribute__((ext_vector_type(8)));

#define HDIM 256
#define NV 10000
#define NE 300000

__device__ __forceinline__ void async16(const bf16_t* g, bf16_t* l) {
  __builtin_amdgcn_global_load_lds(
      (const __attribute__((address_space(1))) void*)g,
      (__attribute__((address_space(3))) void*)l, 16, 0, 0);
}

// fp32 -> bf16 convert + permute both 256x256 weights into fragment order.
// Chunk c (16B = 8 bf16): h=c>>12 (n-half), idx=c&4095, g2=idx>>6 (kstep*8+ni),
// lane=idx&63.  n = h*128 + ni*16 + (lane&15), kb = kstep*32 + (lane>>4)*8.
// In-kernel read: half base + (kstep*8+ni)*1024B + lane*16B.
__global__ __launch_bounds__(256) void cvt_weights(
    const float* __restrict__ us, const float* __restrict__ vs,
    bf16_t* __restrict__ us_o, bf16_t* __restrict__ vs_o) {
  const int c = blockIdx.x * 256 + threadIdx.x;  // 0..8191 (32 blocks)
  const int h = c >> 12;
  const int idx = c & 4095;
  const int g2 = idx >> 6;
  const int ln = idx & 63;
  const int ni = g2 & 7;
  const int ks = g2 >> 3;
  const int n = h * 128 + ni * 16 + (ln & 15);
  const int kb = ks * 32 + (ln >> 4) * 8;
  const float* su = us + n * HDIM + kb;
  const float* sv = vs + n * HDIM + kb;
  f32x4 a0 = *(const f32x4*)su, a1 = *(const f32x4*)(su + 4);
  f32x4 b0 = *(const f32x4*)sv, b1 = *(const f32x4*)(sv + 4);
  f32x8 av = {a0[0], a0[1], a0[2], a0[3], a1[0], a1[1], a1[2], a1[3]};
  f32x8 bv = {b0[0], b0[1], b0[2], b0[3], b1[0], b1[1], b1[2], b1[3]};
  *(bf16x8*)(us_o + c * 8) = __builtin_convertvector(av, bf16x8);
  *(bf16x8*)(vs_o + c * 8) = __builtin_convertvector(bv, bf16x8);
}

template <bool FUSED>
__global__ __launch_bounds__(256, 2) void gemm(
    const float* __restrict__ A,      // M x 256 fp32 (e or x)
    const bf16_t* __restrict__ Wb,    // frag-order 2x32768 bf16 (2 n-halves)
    const float* __restrict__ bias,   // 256 fp32
    const int* __restrict__ sIdxG,    // FUSED: src indices (E)
    const int* __restrict__ dIdxG,    // FUSED: dst indices (E)
    const bf16_t* __restrict__ Vx,    // FUSED: V x 256 bf16
    float* __restrict__ outF,         // FUSED: M x 256 fp32
    bf16_t* __restrict__ outB,        // !FUSED: M x 256 bf16 (Vx scratch)
    int M) {
  // LDS: [0,64K) B half (frag order). Epilogue staging aliases [0,33792).
  __shared__ __align__(16) char smem[65536];

  const int tid = threadIdx.x;  // 0..255
  const int lane = tid & 63;
  const int wave = tid >> 6;   // 0..3: wave owns rows [wave*32, wave*32+32)
  const int l15 = lane & 15;
  const int quad = lane >> 4;  // 0..3

  const int n0 = blockIdx.x * 128;  // x fastest -> n-half pairs L2/L3-adjacent
  const int row0 = blockIdx.y * 128;

  // --- B: stage whole 64KB half once (linear dest; ws already permuted) ---
  const bf16_t* wsHalf = Wb + (size_t)blockIdx.x * 32768;
  bf16_t* lB = (bf16_t*)smem;
#pragma unroll
  for (int i = 0; i < 16; ++i) {
    const int c = tid + i * 256;
    async16(wsHalf + c * 8, lB + c * 8);  // dest = wave-uniform + lane*16 OK
  }

  // --- A: issue the wave's ENTIRE K-slice (32 x f32x4 = 128 VGPR) ---------
  const float* pA[2];
#pragma unroll
  for (int mi = 0; mi < 2; ++mi) {
    int r = row0 + wave * 32 + mi * 16 + l15;
    if (r >= M) r = M - 1;
    pA[mi] = A + (size_t)r * HDIM + quad * 8;
  }
  f32x4 ar[8][2][2];  // [kstep][mi][half-of-8-floats]
#pragma unroll
  for (int ks = 0; ks < 8; ++ks)
#pragma unroll
    for (int mi = 0; mi < 2; ++mi) {
      ar[ks][mi][0] = *(const f32x4*)(pA[mi] + ks * 32);
      ar[ks][mi][1] = *(const f32x4*)(pA[mi] + ks * 32 + 4);
    }

  f32x4 acc[2][8];
#pragma unroll
  for (int mi = 0; mi < 2; ++mi)
#pragma unroll
    for (int ni = 0; ni < 8; ++ni) {
      f32x4 z = {0.f, 0.f, 0.f, 0.f};
      acc[mi][ni] = z;
    }

  __syncthreads();  // vmcnt(0) drain == the BW phase; B LDS + all A ready

  // --- stall-free compute burst: no loads, no barriers --------------------
#pragma unroll
  for (int ks = 0; ks < 8; ++ks) {
    bf16x8 af[2];
#pragma unroll
    for (int mi = 0; mi < 2; ++mi) {
      f32x8 v = {ar[ks][mi][0][0], ar[ks][mi][0][1], ar[ks][mi][0][2],
                 ar[ks][mi][0][3], ar[ks][mi][1][0], ar[ks][mi][1][1],
                 ar[ks][mi][1][2], ar[ks][mi][1][3]};
      af[mi] = __builtin_convertvector(v, bf16x8);
    }
#pragma unroll
    for (int ni = 0; ni < 8; ++ni) {
      bf16x8 bfr = *(const bf16x8*)(smem + (ks * 8 + ni) * 1024 + lane * 16);
#pragma unroll
      for (int mi = 0; mi < 2; ++mi)
        acc[mi][ni] = __builtin_amdgcn_mfma_f32_16x16x32_bf16(
            af[mi], bfr, acc[mi][ni], 0, 0, 0);
    }
  }

  __syncthreads();  // all waves done reading B LDS -> staging may alias it

  // --- epilogue: C/D layout col = lane&15, row = quad*4 + reg --------------
  // Stage acc(+bias) into per-wave [16][132] f32, re-read coalesced:
  // lane map row = lane>>2, 4-col chunk = (lane&3)*4 + i*16 -> bf16x4 gathers
  // + dwordx4 stores. DS in-order within wave => no barrier inside.
  float bcol[8];
#pragma unroll
  for (int ni = 0; ni < 8; ++ni)
    bcol[ni] = bias[n0 + ni * 16 + l15];

  float* stage = (float*)smem + wave * (16 * 132);
  const int srow = lane >> 2;       // 0..15
  const int scol = (lane & 3) * 4;  // 0,4,8,12

#pragma unroll
  for (int mi = 0; mi < 2; ++mi) {
#pragma unroll
    for (int ni = 0; ni < 8; ++ni)
#pragma unroll
      for (int r = 0; r < 4; ++r)
        stage[(quad * 4 + r) * 132 + ni * 16 + l15] = acc[mi][ni][r] + bcol[ni];

    const int row = row0 + wave * 32 + mi * 16 + srow;
    if (row < M) {
      const float* sp = stage + srow * 132;
      if constexpr (FUSED) {
        const int si = sIdxG[row];
        const int di = dIdxG[row];
        const bf16_t* vs = Vx + (size_t)si * HDIM + n0;
        const bf16_t* vd = Vx + (size_t)di * HDIM + n0;
        float* op = outF + (size_t)row * HDIM + n0;
#pragma unroll
        for (int i = 0; i < 8; ++i) {
          const int c = i * 16 + scol;
          f32x4 a = *(const f32x4*)(sp + c);
          f32x4 sf = __builtin_convertvector(*(const bf16x4*)(vs + c), f32x4);
          f32x4 df = __builtin_convertvector(*(const bf16x4*)(vd + c), f32x4);
          *(f32x4*)(op + c) = a + sf + df;
        }
      } else {
        bf16_t* op = outB + (size_t)row * HDIM + n0;
#pragma unroll
        for (int i = 0; i < 8; ++i) {
          const int c = i * 16 + scol;
          f32x4 a = *(const f32x4*)(sp + c);
          *(bf16x4*)(op + c) = __builtin_convertvector(a, bf16x4);
        }
      }
    }
  }
}

extern "C" void kernel_launch(void* const* d_in, const int* in_sizes, int n_in,
                              void* d_out, int out_size, void* d_ws,
                              size_t ws_size, hipStream_t stream) {
  const float* x = (const float*)d_in[0];     // (V, H) fp32
  const float* e = (const float*)d_in[1];     // (E, H) fp32
  const int* edge = (const int*)d_in[2];      // (2, E) int32: src then dst
  const float* Us_w = (const float*)d_in[3];  // (H, H) fp32
  const float* Us_b = (const float*)d_in[4];  // (H,) fp32
  const float* Vs_w = (const float*)d_in[5];  // (H, H) fp32
  const float* Vs_b = (const float*)d_in[6];  // (H,) fp32
  float* out = (float*)d_out;                 // (E, H) fp32

  bf16_t* us_w_b = (bf16_t*)d_ws;                         // 128 KB frag-order
  bf16_t* vs_w_b = (bf16_t*)((char*)d_ws + (128 << 10));  // 128 KB frag-order
  bf16_t* Vx = (bf16_t*)((char*)d_ws + (256 << 10));      // 5.12 MB

  dim3 blk(256, 1, 1);

  cvt_weights<<<dim3(32, 1, 1), blk, 0, stream>>>(Us_w, Vs_w, us_w_b, vs_w_b);

  dim3 g1(2, (NV + 127) / 128, 1);
  gemm<false><<<g1, blk, 0, stream>>>(x, vs_w_b, Vs_b, nullptr, nullptr,
                                      nullptr, nullptr, Vx, NV);

  dim3 g2(2, (NE + 127) / 128, 1);
  gemm<true><<<g2, blk, 0, stream>>>(e, us_w_b, Us_b, edge, edge + NE, Vx, out,
                                     nullptr, NE);
}